// Round 11
// baseline (203.940 us; speedup 1.0000x reference)
//
#include <hip/hip_runtime.h>
#include <hip/hip_bf16.h>

typedef __attribute__((ext_vector_type(4))) int i32x4;
typedef __attribute__((ext_vector_type(16))) int i32x16;

#define M_DIM 8192
#define N_DIM 8192
#define K_DIM 2048
#define WCOUNT (N_DIM * K_DIM)

// Fragment-major layout for both quantized tensors:
//   frag[t32][kc][l] : byte = t32*65536 + kc*512 + l*16
// holds rows r = t32*32 + l (l=0..31), k = kc*16 .. kc*16+15.
// A wave-load of one 32x32x32 MFMA operand fragment (lane = kg*32+l31 reads
// row l31, chunk 2ks+kg) is then a CONTIGUOUS 1024-B access: base + lane*16.

// ---------------- kernel 1: per-block partial sums of |w| ----------------
__global__ __launch_bounds__(256) void k_abs_partial(const float* __restrict__ w,
                                                     float* __restrict__ part) {
    int tid = blockIdx.x * 256 + threadIdx.x;
    const float4* w4 = (const float4*)w;
    float s = 0.0f;
    const int total4 = WCOUNT / 4;
    for (int i = tid; i < total4; i += 2048 * 256) {
        float4 v = w4[i];
        s += fabsf(v.x) + fabsf(v.y) + fabsf(v.z) + fabsf(v.w);
    }
    #pragma unroll
    for (int off = 1; off < 64; off <<= 1) s += __shfl_xor(s, off);
    __shared__ float red[4];
    if ((threadIdx.x & 63) == 0) red[threadIdx.x >> 6] = s;
    __syncthreads();
    if (threadIdx.x == 0)
        part[blockIdx.x] = (red[0] + red[1]) + (red[2] + red[3]);
}

// ---------------- kernel 2: deterministic final reduce -> sum|w| ----------------
__global__ __launch_bounds__(256) void k_abs_final(const float* __restrict__ part,
                                                   float* __restrict__ sum) {
    int t = threadIdx.x;
    float s = 0.0f;
    #pragma unroll
    for (int i = 0; i < 8; i++) s += part[t + i * 256];
    #pragma unroll
    for (int off = 1; off < 64; off <<= 1) s += __shfl_xor(s, off);
    __shared__ float red[4];
    if ((t & 63) == 0) red[t >> 6] = s;
    __syncthreads();
    if (t == 0) sum[0] = (red[0] + red[1]) + (red[2] + red[3]);
}

// -------- kernel 3: ternary weight quant -> int8, FRAGMENT-MAJOR layout --------
// thread g = n*128 + kc: reads w[n][kc*16..+15] (coalesced: wave = 4 KB run),
// writes 16 B chunk at (n>>5)*65536 + kc*512 + (n&31)*16.
__global__ __launch_bounds__(256) void k_wquant(const float* __restrict__ w,
                                                const float* __restrict__ sum,
                                                signed char* __restrict__ wqf) {
    const float thr = 0.5f * (sum[0] * (1.0f / 16777216.0f));
    const int g = blockIdx.x * 256 + threadIdx.x;   // 0 .. 8192*128-1
    const int n = g >> 7;
    const int kc = g & 127;
    const float4* wr = (const float4*)(w + (size_t)n * K_DIM + kc * 16);
    union { signed char c[16]; uint4 v; } pk;
    #pragma unroll
    for (int q = 0; q < 4; q++) {
        float4 v = wr[q];
        pk.c[q * 4 + 0] = v.x > thr ? 1 : (v.x < -thr ? -1 : 0);
        pk.c[q * 4 + 1] = v.y > thr ? 1 : (v.y < -thr ? -1 : 0);
        pk.c[q * 4 + 2] = v.z > thr ? 1 : (v.z < -thr ? -1 : 0);
        pk.c[q * 4 + 3] = v.w > thr ? 1 : (v.w < -thr ? -1 : 0);
    }
    *(uint4*)(wqf + (size_t)(n >> 5) * 65536 + kc * 512 + (n & 31) * 16) = pk.v;
}

// -------- kernel 4: activation quant -> int8 fragment-major + scale --------
// block = row r; thread t holds k = 8t..8t+7; writes 8 B at fragment address.
__global__ __launch_bounds__(256) void k_xquant(const float* __restrict__ x,
                                                signed char* __restrict__ xqf,
                                                float* __restrict__ scale) {
    const int row = blockIdx.x;
    const int t = threadIdx.x;
    const float4* xr = (const float4*)(x + (size_t)row * K_DIM);
    float4 a = xr[t * 2];
    float4 b = xr[t * 2 + 1];
    float m = fmaxf(fmaxf(fmaxf(fabsf(a.x), fabsf(a.y)), fmaxf(fabsf(a.z), fabsf(a.w))),
                    fmaxf(fmaxf(fabsf(b.x), fabsf(b.y)), fmaxf(fabsf(b.z), fabsf(b.w))));
    #pragma unroll
    for (int off = 1; off < 64; off <<= 1) m = fmaxf(m, __shfl_xor(m, off));
    __shared__ float red[4];
    if ((t & 63) == 0) red[t >> 6] = m;
    __syncthreads();
    m = fmaxf(fmaxf(red[0], red[1]), fmaxf(red[2], red[3]));
    const float sc = fmaxf(m, 1e-5f);
    if (t == 0) scale[row] = sc;
    const float r = 127.0f / sc;
    float q[8] = {a.x, a.y, a.z, a.w, b.x, b.y, b.z, b.w};
    union { signed char c[8]; uint2 v; } pk;
    #pragma unroll
    for (int j = 0; j < 8; j++) {
        float v = rintf(q[j] * r);
        v = fminf(fmaxf(v, -127.0f), 127.0f);
        pk.c[j] = (signed char)v;
    }
    *(uint2*)(xqf + (size_t)(row >> 5) * 65536 + (t >> 1) * 512
              + (row & 31) * 16 + (t & 1) * 8) = pk.v;
}

// ---------------- kernel 4b: per-row epilogue coefficient ----------------
__global__ __launch_bounds__(256) void k_coef(const float* __restrict__ sum,
                                              const float* __restrict__ scale,
                                              float* __restrict__ coef) {
    const int i = blockIdx.x * 256 + threadIdx.x;
    coef[i] = (sum[0] * (1.0f / 16777216.0f)) / scale[i];
}

// ---------------- kernel 5: 128x256 i8 GEMM, B direct-to-register ----------------
// out[M][N] fp32 = relu(acc*coef)^2.  512 thr / 8 waves (2Mx4N), wave 64x64 out
// = 2x2 of mfma_i32_32x32x32 (acc 64 AGPR). A: fragment-major xqf staged via ONE
// GLDS16/thread/K-tile into linear LDS (2 bufs x 8 KB); every ds_read_b128 is
// wave-contiguous (base + lane*16) -> conflict-free by construction. B: loaded
// global->register from fragment-major wqf as 1024-B coalesced wave loads
// (L2-resident panel; register double-buffer, compiler-tracked). LDS traffic
// drops 2.2x vs R10 -> below MFMA demand; 2 blocks/CU keeps epilogue overlap.
// vmcnt ledger (B loads counted): in-loop gates vmcnt(5) = {A(kt+1), B(kt+1)x4,
// A(kt+2)} outstanding, forcing A(kt+1) staged one full iter earlier.
#define GLDS16(g, l)                                                                   \
    __builtin_amdgcn_global_load_lds((const __attribute__((address_space(1))) void*)(g), \
                                     (__attribute__((address_space(3))) void*)(l), 16, 0, 0)

#define BAR __builtin_amdgcn_s_barrier()
#define VMCNT5 asm volatile("s_waitcnt vmcnt(5)" ::: "memory")
#define VMCNT4 asm volatile("s_waitcnt vmcnt(4)" ::: "memory")

__global__ __launch_bounds__(512, 4) void k_gemm(const signed char* __restrict__ xqf,
                                                 const signed char* __restrict__ wqf,
                                                 const float* __restrict__ coef,
                                                 float* __restrict__ out) {
    __shared__ signed char lds[16384];

    const int t = threadIdx.x;
    const int lane = t & 63;
    const int wid = t >> 6;        // 0..7
    const int wm = wid >> 2;       // 0..1  (M half: 64 rows)
    const int wn = wid & 3;        // 0..3  (N quarter: 64 cols)
    const int l31 = lane & 31;
    const int kg = lane >> 5;

    // L2 mapping: XCD x owns brows [8x,8x+8); per XCD, groups of 4 bcols sweep.
    const int bid = blockIdx.x;
    const int xcd = bid & 7;
    const int idx = bid >> 3;                 // 0..255
    const int bcol = (idx >> 5) * 4 + (idx & 3);
    const int brow = xcd * 8 + ((idx >> 2) & 7);

    // A staging: thread t stages chunk t (m32l = t>>7, kcl = (t>>5)&3, l = t&31);
    // per-wave source is contiguous 1024 B; LDS dest linear (byte t*16).
    const signed char* aSrc = xqf + (size_t)(brow * 4 + (t >> 7)) * 65536
                              + ((t >> 5) & 3) * 512 + (t & 31) * 16;
    const int aDst = wid * 1024;              // + lane*16 implicit

    // B global per-lane base: fragment (nt, ks) at K-tile kt is
    // bSrc + nt*65536 + kt*2048 + ks*1024  (contiguous 1024 B per wave).
    const signed char* bSrc = wqf + (size_t)(bcol * 8 + wn * 2) * 65536 + lane * 16;

    // A LDS read base: frag (mt, ks) at buf b = b*8192 + (wm*2+mt)*2048 + ks*1024
    // + lane*16 (contiguous per wave).
    const int aRd = wm * 4096 + lane * 16;

    i32x16 acc00 = (i32x16){0,0,0,0,0,0,0,0,0,0,0,0,0,0,0,0};
    i32x16 acc01 = acc00, acc10 = acc00, acc11 = acc00;

#define STG_A(buf, kt) GLDS16(aSrc + (size_t)(kt) * 2048, lds + (buf) * 8192 + aDst)
#define LOADB(B0, B1, B2, B3, kt) do {                                             \
        B0 = *(const i32x4*)(bSrc + (size_t)(kt) * 2048);                          \
        B1 = *(const i32x4*)(bSrc + (size_t)(kt) * 2048 + 65536);                  \
        B2 = *(const i32x4*)(bSrc + (size_t)(kt) * 2048 + 1024);                   \
        B3 = *(const i32x4*)(bSrc + (size_t)(kt) * 2048 + 66560); } while (0)
#define HALF(buf, B0, B1, B2, B3) do {                                             \
        i32x4 a0 = *(const i32x4*)&lds[(buf) * 8192 + aRd];                        \
        i32x4 a1 = *(const i32x4*)&lds[(buf) * 8192 + aRd + 2048];                 \
        __builtin_amdgcn_s_setprio(1);                                             \
        acc00 = __builtin_amdgcn_mfma_i32_32x32x32_i8(a0, B0, acc00, 0, 0, 0);     \
        acc01 = __builtin_amdgcn_mfma_i32_32x32x32_i8(a0, B1, acc01, 0, 0, 0);     \
        acc10 = __builtin_amdgcn_mfma_i32_32x32x32_i8(a1, B0, acc10, 0, 0, 0);     \
        acc11 = __builtin_amdgcn_mfma_i32_32x32x32_i8(a1, B1, acc11, 0, 0, 0);     \
        __builtin_amdgcn_s_setprio(0);                                             \
        a0 = *(const i32x4*)&lds[(buf) * 8192 + aRd + 1024];                       \
        a1 = *(const i32x4*)&lds[(buf) * 8192 + aRd + 3072];                       \
        __builtin_amdgcn_s_setprio(1);                                             \
        acc00 = __builtin_amdgcn_mfma_i32_32x32x32_i8(a0, B2, acc00, 0, 0, 0);     \
        acc01 = __builtin_amdgcn_mfma_i32_32x32x32_i8(a0, B3, acc01, 0, 0, 0);     \
        acc10 = __builtin_amdgcn_mfma_i32_32x32x32_i8(a1, B2, acc10, 0, 0, 0);     \
        acc11 = __builtin_amdgcn_mfma_i32_32x32x32_i8(a1, B3, acc11, 0, 0, 0);     \
        __builtin_amdgcn_s_setprio(0); } while (0)

    i32x4 BA0, BA1, BA2, BA3, BB0, BB1, BB2, BB3;

    // ---- prologue: A(0)->buf0, A(1)->buf1, B(0)->regs; force A(0).
    STG_A(0, 0);
    STG_A(1, 1);
    LOADB(BA0, BA1, BA2, BA3, 0);
    VMCNT5;                    // {A0,A1,B0x4}=6 -> forces A(0)
    BAR;

    #pragma unroll 1
    for (int j = 0; j < 15; j++) {
        const int kt = 2 * j;
        // kt (buf0, BA)
        LOADB(BB0, BB1, BB2, BB3, kt + 1);
        HALF(0, BA0, BA1, BA2, BA3);
        BAR;                           // buf0 reads done (all waves)
        STG_A(0, kt + 2);
        VMCNT5;                        // {A(kt+1), B(kt+1)x4, A(kt+2)} -> forces A(kt+1)
        BAR;
        // kt+1 (buf1, BB)
        LOADB(BA0, BA1, BA2, BA3, kt + 2);
        HALF(1, BB0, BB1, BB2, BB3);
        BAR;
        STG_A(1, kt + 3);
        VMCNT5;                        // forces A(kt+2)
        BAR;
    }
    // ---- peel kt=30 (buf0, BA=B(30)), kt=31 (buf1, BB=B(31))
    LOADB(BB0, BB1, BB2, BB3, 31);
    HALF(0, BA0, BA1, BA2, BA3);
    BAR;
    VMCNT4;                            // {A(31), B(31)x4}=5 -> forces A(31)
    BAR;
    HALF(1, BB0, BB1, BB2, BB3);

    // ---- epilogue: out = (max(acc * coef[row], 0))^2, nontemporal stores.
    // 32x32 C/D: col = lane&31, row = (r&3) + 8*(r>>2) + 4*(lane>>5)
    const int rb = brow * 128 + wm * 64 + 4 * kg;
    const int cb = bcol * 256 + wn * 64 + l31;
    #pragma unroll
    for (int mt = 0; mt < 2; mt++) {
        const i32x16 ac0 = mt ? acc10 : acc00;
        const i32x16 ac1 = mt ? acc11 : acc01;
        #pragma unroll
        for (int r = 0; r < 16; r++) {
            const int grow = rb + mt * 32 + (r & 3) + 8 * (r >> 2);
            const float c = coef[grow];
            float v0 = (float)ac0[r] * c; v0 = fmaxf(v0, 0.0f);
            float v1 = (float)ac1[r] * c; v1 = fmaxf(v1, 0.0f);
            __builtin_nontemporal_store(v0 * v0, &out[(size_t)grow * N_DIM + cb]);
            __builtin_nontemporal_store(v1 * v1, &out[(size_t)grow * N_DIM + cb + 32]);
        }
    }
#undef STG_A
#undef LOADB
#undef HALF
}

// ---------------- launch ----------------
extern "C" void kernel_launch(void* const* d_in, const int* in_sizes, int n_in,
                              void* d_out, int out_size, void* d_ws, size_t ws_size,
                              hipStream_t stream) {
    const float* x = (const float*)d_in[0];   // [4,2048,2048] fp32
    const float* w = (const float*)d_in[1];   // [8192,2048] fp32
    float* out = (float*)d_out;               // [4,2048,8192] fp32

    char* ws = (char*)d_ws;
    float* sum   = (float*)ws;                          // 1 float
    float* part  = (float*)(ws + 256);                  // 2048 floats
    float* scale = (float*)(ws + 16384);                // 8192 floats
    float* coef  = (float*)(ws + 49152);                // 8192 floats
    signed char* xqf = (signed char*)(ws + 131072);              // 16.78 MB
    signed char* wqf = (signed char*)(ws + 131072 + 16777216);   // 16.78 MB

    k_abs_partial<<<2048, 256, 0, stream>>>(w, part);
    k_abs_final<<<1, 256, 0, stream>>>(part, sum);
    k_wquant<<<4096, 256, 0, stream>>>(w, sum, wqf);
    k_xquant<<<M_DIM, 256, 0, stream>>>(x, xqf, scale);
    k_coef<<<32, 256, 0, stream>>>(sum, scale, coef);
    k_gemm<<<dim3(2048), 512, 0, stream>>>(xqf, wqf, coef, out);
}

// Round 12
// 196.732 us; speedup vs baseline: 1.0366x; 1.0366x over previous
//
#include <hip/hip_runtime.h>
#include <hip/hip_bf16.h>

typedef __attribute__((ext_vector_type(4))) int i32x4;
typedef __attribute__((ext_vector_type(16))) int i32x16;

#define M_DIM 8192
#define N_DIM 8192
#define K_DIM 2048
#define WCOUNT (N_DIM * K_DIM)

// Fragment-major layout for both quantized tensors:
//   frag[t32][kc][l] : byte = t32*65536 + kc*512 + l*16
// holds rows r = t32*32 + l (l=0..31), k = kc*16 .. kc*16+15.
// One 32x32x32 MFMA operand fragment is a CONTIGUOUS 1024-B wave access.

// ---------------- kernel 1: per-block partial sums of |w| ----------------
__global__ __launch_bounds__(256) void k_abs_partial(const float* __restrict__ w,
                                                     float* __restrict__ part) {
    int tid = blockIdx.x * 256 + threadIdx.x;
    const float4* w4 = (const float4*)w;
    float s = 0.0f;
    const int total4 = WCOUNT / 4;
    for (int i = tid; i < total4; i += 2048 * 256) {
        float4 v = w4[i];
        s += fabsf(v.x) + fabsf(v.y) + fabsf(v.z) + fabsf(v.w);
    }
    #pragma unroll
    for (int off = 1; off < 64; off <<= 1) s += __shfl_xor(s, off);
    __shared__ float red[4];
    if ((threadIdx.x & 63) == 0) red[threadIdx.x >> 6] = s;
    __syncthreads();
    if (threadIdx.x == 0)
        part[blockIdx.x] = (red[0] + red[1]) + (red[2] + red[3]);
}

// ---------------- kernel 2: deterministic final reduce -> sum|w| ----------------
__global__ __launch_bounds__(256) void k_abs_final(const float* __restrict__ part,
                                                   float* __restrict__ sum) {
    int t = threadIdx.x;
    float s = 0.0f;
    #pragma unroll
    for (int i = 0; i < 8; i++) s += part[t + i * 256];
    #pragma unroll
    for (int off = 1; off < 64; off <<= 1) s += __shfl_xor(s, off);
    __shared__ float red[4];
    if ((t & 63) == 0) red[t >> 6] = s;
    __syncthreads();
    if (t == 0) sum[0] = (red[0] + red[1]) + (red[2] + red[3]);
}

// -------- kernel 3: ternary weight quant -> int8, fragment-major --------
__global__ __launch_bounds__(256) void k_wquant(const float* __restrict__ w,
                                                const float* __restrict__ sum,
                                                signed char* __restrict__ wqf) {
    const float thr = 0.5f * (sum[0] * (1.0f / 16777216.0f));
    const int g = blockIdx.x * 256 + threadIdx.x;   // 0 .. 8192*128-1
    const int n = g >> 7;
    const int kc = g & 127;
    const float4* wr = (const float4*)(w + (size_t)n * K_DIM + kc * 16);
    union { signed char c[16]; uint4 v; } pk;
    #pragma unroll
    for (int q = 0; q < 4; q++) {
        float4 v = wr[q];
        pk.c[q * 4 + 0] = v.x > thr ? 1 : (v.x < -thr ? -1 : 0);
        pk.c[q * 4 + 1] = v.y > thr ? 1 : (v.y < -thr ? -1 : 0);
        pk.c[q * 4 + 2] = v.z > thr ? 1 : (v.z < -thr ? -1 : 0);
        pk.c[q * 4 + 3] = v.w > thr ? 1 : (v.w < -thr ? -1 : 0);
    }
    *(uint4*)(wqf + (size_t)(n >> 5) * 65536 + kc * 512 + (n & 31) * 16) = pk.v;
}

// -------- kernel 4: activation quant -> int8 fragment-major + scale --------
__global__ __launch_bounds__(256) void k_xquant(const float* __restrict__ x,
                                                signed char* __restrict__ xqf,
                                                float* __restrict__ scale) {
    const int row = blockIdx.x;
    const int t = threadIdx.x;
    const float4* xr = (const float4*)(x + (size_t)row * K_DIM);
    float4 a = xr[t * 2];
    float4 b = xr[t * 2 + 1];
    float m = fmaxf(fmaxf(fmaxf(fabsf(a.x), fabsf(a.y)), fmaxf(fabsf(a.z), fabsf(a.w))),
                    fmaxf(fmaxf(fabsf(b.x), fabsf(b.y)), fmaxf(fabsf(b.z), fabsf(b.w))));
    #pragma unroll
    for (int off = 1; off < 64; off <<= 1) m = fmaxf(m, __shfl_xor(m, off));
    __shared__ float red[4];
    if ((t & 63) == 0) red[t >> 6] = m;
    __syncthreads();
    m = fmaxf(fmaxf(red[0], red[1]), fmaxf(red[2], red[3]));
    const float sc = fmaxf(m, 1e-5f);
    if (t == 0) scale[row] = sc;
    const float r = 127.0f / sc;
    float q[8] = {a.x, a.y, a.z, a.w, b.x, b.y, b.z, b.w};
    union { signed char c[8]; uint2 v; } pk;
    #pragma unroll
    for (int j = 0; j < 8; j++) {
        float v = rintf(q[j] * r);
        v = fminf(fmaxf(v, -127.0f), 127.0f);
        pk.c[j] = (signed char)v;
    }
    *(uint2*)(xqf + (size_t)(row >> 5) * 65536 + (t >> 1) * 512
              + (row & 31) * 16 + (t & 1) * 8) = pk.v;
}

// ---------------- kernel 4b: per-row epilogue coefficient ----------------
__global__ __launch_bounds__(256) void k_coef(const float* __restrict__ sum,
                                              const float* __restrict__ scale,
                                              float* __restrict__ coef) {
    const int i = blockIdx.x * 256 + threadIdx.x;
    coef[i] = (sum[0] * (1.0f / 16777216.0f)) / scale[i];
}

// ---------------- kernel 5: 128x128 i8 GEMM, 3 blocks/CU, 3-buf ring ----------
// out = relu(acc*coef)^2. 256 thr / 4 waves (2Mx2N), wave 64x64 = 2x2 of
// mfma_i32_32x32x32 (acc 64 AGPR). LDS 48 KiB = 3-buffer ring x (A 8K + B 8K),
// all fragment-major -> every ds_read_b128 and GLDS dest is wave-contiguous
// (conflict-free by construction, R11-verified). 3 blocks/CU (3 independent
// barrier domains) + 16 sequential blocks/CU: block rotation interleaves
// prologue/K-loop/epilogue phases across the CU — attacks the convoy that
// pinned R4-R11 at ~37% MfmaUtil (2 lockstep blocks, synchronized epilogues).
// Ring ledger (exact counts; GLDS are the only in-loop VMEM): step k reads
// buf k%3, restages it as k+3 AFTER the read-barrier; gate vmcnt(8) leaves
// {k+2,k+3} outstanding, forcing k+1 (issued 2 K-tile walls earlier). Tail
// gates 8 -> 4 -> 0.
#define GLDS16(g, l)                                                                   \
    __builtin_amdgcn_global_load_lds((const __attribute__((address_space(1))) void*)(g), \
                                     (__attribute__((address_space(3))) void*)(l), 16, 0, 0)

#define BAR __builtin_amdgcn_s_barrier()
#define VMW(n) asm volatile("s_waitcnt vmcnt(" #n ")" ::: "memory")

__global__ __launch_bounds__(256, 3) void k_gemm(const signed char* __restrict__ xqf,
                                                 const signed char* __restrict__ wqf,
                                                 const float* __restrict__ coef,
                                                 float* __restrict__ out) {
    __shared__ signed char lds[49152];

    const int t = threadIdx.x;
    const int lane = t & 63;
    const int wid = t >> 6;        // 0..3
    const int wm = wid >> 1;       // 0..1  (M half: 64 rows)
    const int wn = wid & 1;        // 0..1  (N half: 64 cols)
    const int l31 = lane & 31;
    const int kg = lane >> 5;

    // L2 mapping: XCD x owns brows [8x,8x+8) (A slice 2 MB L2-resident);
    // per XCD: 16 groups of 4 bcols, each sweeping 8 brows x 4 bcols.
    const int bid = blockIdx.x;                 // 0..4095
    const int xcd = bid & 7;
    const int idx = bid >> 3;                   // 0..511
    const int grp = idx >> 5;                   // 0..15
    const int w_ = idx & 31;
    const int bcol = grp * 4 + (w_ & 3);        // 0..63
    const int brow = xcd * 8 + ((w_ >> 2) & 7); // 0..63

    // staging: thread t covers chunks c=t and c=t+256 of each 8 KB region
    // (region = 4 t32-tiles x 2048 B, contiguous per K-tile in fragment-major).
    const signed char* aSrc0 = xqf + (size_t)(brow * 4 + (t >> 7)) * 65536 + (t & 127) * 16;
    const signed char* aSrc1 = xqf + (size_t)(brow * 4 + 2 + (t >> 7)) * 65536 + (t & 127) * 16;
    const signed char* bSrc0 = wqf + (size_t)(bcol * 4 + (t >> 7)) * 65536 + (t & 127) * 16;
    const signed char* bSrc1 = wqf + (size_t)(bcol * 4 + 2 + (t >> 7)) * 65536 + (t & 127) * 16;
    const int dst0 = wid * 1024;               // chunk c=t   (+ lane*16 implicit)
    const int dst1 = 4096 + wid * 1024;        // chunk c=t+256

#define STG(bufc, kt) do {                                                         \
        GLDS16(aSrc0 + (size_t)(kt) * 2048, lds + (bufc) * 16384 + dst0);          \
        GLDS16(aSrc1 + (size_t)(kt) * 2048, lds + (bufc) * 16384 + dst1);          \
        GLDS16(bSrc0 + (size_t)(kt) * 2048, lds + (bufc) * 16384 + 8192 + dst0);   \
        GLDS16(bSrc1 + (size_t)(kt) * 2048, lds + (bufc) * 16384 + 8192 + dst1);   \
    } while (0)

    // fragment reads (contiguous per wave): A (mt,ks): (wm*2+mt)*2048 + ks*1024
    // + lane*16; B: 8192 + (wn*2+nt)*2048 + ks*1024 + lane*16.
    const int aRd = wm * 4096 + lane * 16;
    const int bRd = 8192 + wn * 4096 + lane * 16;

    i32x16 acc00 = (i32x16){0,0,0,0,0,0,0,0,0,0,0,0,0,0,0,0};
    i32x16 acc01 = acc00, acc10 = acc00, acc11 = acc00;

#define MMK(bufc) do {                                                             \
        const int ab = (bufc) * 16384 + aRd;                                       \
        const int bb = (bufc) * 16384 + bRd;                                       \
        i32x4 a00 = *(const i32x4*)&lds[ab];                                       \
        i32x4 a10 = *(const i32x4*)&lds[ab + 2048];                                \
        i32x4 b00 = *(const i32x4*)&lds[bb];                                       \
        i32x4 b10 = *(const i32x4*)&lds[bb + 2048];                                \
        i32x4 a01 = *(const i32x4*)&lds[ab + 1024];                                \
        i32x4 a11 = *(const i32x4*)&lds[ab + 3072];                                \
        i32x4 b01 = *(const i32x4*)&lds[bb + 1024];                                \
        i32x4 b11 = *(const i32x4*)&lds[bb + 3072];                                \
        __builtin_amdgcn_s_setprio(1);                                             \
        acc00 = __builtin_amdgcn_mfma_i32_32x32x32_i8(a00, b00, acc00, 0, 0, 0);   \
        acc01 = __builtin_amdgcn_mfma_i32_32x32x32_i8(a00, b10, acc01, 0, 0, 0);   \
        acc10 = __builtin_amdgcn_mfma_i32_32x32x32_i8(a10, b00, acc10, 0, 0, 0);   \
        acc11 = __builtin_amdgcn_mfma_i32_32x32x32_i8(a10, b10, acc11, 0, 0, 0);   \
        acc00 = __builtin_amdgcn_mfma_i32_32x32x32_i8(a01, b01, acc00, 0, 0, 0);   \
        acc01 = __builtin_amdgcn_mfma_i32_32x32x32_i8(a01, b11, acc01, 0, 0, 0);   \
        acc10 = __builtin_amdgcn_mfma_i32_32x32x32_i8(a11, b01, acc10, 0, 0, 0);   \
        acc11 = __builtin_amdgcn_mfma_i32_32x32x32_i8(a11, b11, acc11, 0, 0, 0);   \
        __builtin_amdgcn_s_setprio(0); } while (0)

    // step k (0..26 steady): reads+MFMA buf k%3; BAR; restage k+3; vmcnt(8); BAR.
#define STEP(bufc, kt) do {                                                        \
        MMK(bufc);                                                                 \
        BAR;                                                                       \
        STG(bufc, (kt) + 3);                                                       \
        VMW(8);                                                                    \
        BAR; } while (0)

    // ---- prologue: stage kt0..kt2 into bufs 0..2; force kt0.
    STG(0, 0); STG(1, 1); STG(2, 2);
    VMW(8);
    BAR;

    #pragma unroll 1
    for (int j = 0; j < 9; j++) {
        const int kt = 3 * j;
        STEP(0, kt);
        STEP(1, kt + 1);
        STEP(2, kt + 2);
    }
    // ---- tail: kt 27..31
    STEP(0, 27);                       // stages 30, gate 8 (forces 28)
    STEP(1, 28);                       // stages 31, gate 8 (forces 29)
    MMK(2); BAR; VMW(4); BAR;          // kt29: no stage; forces 30
    MMK(0); BAR; VMW(0); BAR;          // kt30: forces 31
    MMK(1);                            // kt31

    // ---- epilogue: out = (max(acc * coef[row], 0))^2, nontemporal stores.
    // 32x32 C/D: col = lane&31, row = (r&3) + 8*(r>>2) + 4*(lane>>5)
    const int rb = brow * 128 + wm * 64 + 4 * kg;
    const int cb = bcol * 128 + wn * 64 + l31;
    #pragma unroll
    for (int mt = 0; mt < 2; mt++) {
        const i32x16 ac0 = mt ? acc10 : acc00;
        const i32x16 ac1 = mt ? acc11 : acc01;
        #pragma unroll
        for (int r = 0; r < 16; r++) {
            const int grow = rb + mt * 32 + (r & 3) + 8 * (r >> 2);
            const float c = coef[grow];
            float v0 = (float)ac0[r] * c; v0 = fmaxf(v0, 0.0f);
            float v1 = (float)ac1[r] * c; v1 = fmaxf(v1, 0.0f);
            __builtin_nontemporal_store(v0 * v0, &out[(size_t)grow * N_DIM + cb]);
            __builtin_nontemporal_store(v1 * v1, &out[(size_t)grow * N_DIM + cb + 32]);
        }
    }
#undef STG
#undef MMK
#undef STEP
}

// ---------------- launch ----------------
extern "C" void kernel_launch(void* const* d_in, const int* in_sizes, int n_in,
                              void* d_out, int out_size, void* d_ws, size_t ws_size,
                              hipStream_t stream) {
    const float* x = (const float*)d_in[0];   // [4,2048,2048] fp32
    const float* w = (const float*)d_in[1];   // [8192,2048] fp32
    float* out = (float*)d_out;               // [4,2048,8192] fp32

    char* ws = (char*)d_ws;
    float* sum   = (float*)ws;                          // 1 float
    float* part  = (float*)(ws + 256);                  // 2048 floats
    float* scale = (float*)(ws + 16384);                // 8192 floats
    float* coef  = (float*)(ws + 49152);                // 8192 floats
    signed char* xqf = (signed char*)(ws + 131072);              // 16.78 MB
    signed char* wqf = (signed char*)(ws + 131072 + 16777216);   // 16.78 MB

    k_abs_partial<<<2048, 256, 0, stream>>>(w, part);
    k_abs_final<<<1, 256, 0, stream>>>(part, sum);
    k_wquant<<<4096, 256, 0, stream>>>(w, sum, wqf);
    k_xquant<<<M_DIM, 256, 0, stream>>>(x, xqf, scale);
    k_coef<<<32, 256, 0, stream>>>(sum, scale, coef);
    k_gemm<<<dim3(4096), 256, 0, stream>>>(xqf, wqf, coef, out);
}